// Round 1
// baseline (128.426 us; speedup 1.0000x reference)
//
#include <hip/hip_runtime.h>

// Shapes (fixed by the reference): B=1, M=N=256, O=P=12, C=128, D=32
#define N_ 256
#define M_ 256
#define O_ 12
#define C_ 128
#define D_ 32

// rk[p,o,c] = sum_d fkb[p,o,d] * Wr[d,c]   -- (12*12*128 outputs)
__global__ __launch_bounds__(256) void rot_proj_kernel(
    const float* __restrict__ fkb, const float* __restrict__ Wr,
    float* __restrict__ rk)
{
    int idx = blockIdx.x * 256 + threadIdx.x;
    if (idx >= O_ * O_ * C_) return;
    int c  = idx & (C_ - 1);
    int po = idx >> 7;                 // p*O + o
    const float* f = fkb + po * D_;
    float acc = 0.f;
#pragma unroll
    for (int d = 0; d < D_; ++d) acc = fmaf(f[d], Wr[d * C_ + c], acc);
    rk[idx] = acc;
}

// y1[m,o,c] = sum_d Ws[d,c] * ( sum_n kb[m,n,o,d] * x[n,o,c] * mask[n] )
// One block per (m,o). 256 threads = 2 n-halves x 128 c-lanes.
__global__ __launch_bounds__(256) void spatial_kernel(
    const float* __restrict__ x,     // [N][O][C]
    const float* __restrict__ kb,    // [M][N][O][D]
    const float* __restrict__ mask,  // [N]
    const float* __restrict__ Ws,    // [D][C]
    float* __restrict__ y1)          // [M][O][C]
{
    const int bid = blockIdx.x;
    const int m   = bid / O_;
    const int o   = bid % O_;
    const int tid = threadIdx.x;
    const int h   = tid >> 7;        // which n-half (0/1)
    const int c   = tid & (C_ - 1);

    __shared__ float kbs[2][8][D_];      // 2 KB: 8 kb rows per half
    __shared__ float msk[N_];            // 1 KB
    __shared__ float Ts[2][D_][C_];      // 32 KB: cross-half reduce

    msk[tid] = mask[tid];                // N_ == blockDim.x

    float T[D_];
#pragma unroll
    for (int d = 0; d < D_; ++d) T[d] = 0.f;

    const float* kb_mo = kb + (size_t)m * (N_ * O_ * D_) + o * D_;
    const int j_ld = c >> 4;             // 0..7  (row within chunk)
    const int d_ld = (c & 15) * 2;       // 0..30 (float2 within row)

    for (int chunk = 0; chunk < 16; ++chunk) {
        const int n0 = h * 128 + chunk * 8;
        __syncthreads();  // protect kbs overwrite (and msk visibility on iter 0)
        float2 v = *reinterpret_cast<const float2*>(
            kb_mo + (size_t)(n0 + j_ld) * (O_ * D_) + d_ld);
        kbs[h][j_ld][d_ld]     = v.x;
        kbs[h][j_ld][d_ld + 1] = v.y;
        __syncthreads();
#pragma unroll
        for (int j = 0; j < 8; ++j) {
            const int n = n0 + j;
            const float xv = x[(n * O_ + o) * C_ + c] * msk[n];
#pragma unroll
            for (int d = 0; d < D_; ++d)
                T[d] = fmaf(kbs[h][j][d], xv, T[d]);  // LDS broadcast read
        }
    }

#pragma unroll
    for (int d = 0; d < D_; ++d) Ts[h][d][c] = T[d];
    __syncthreads();
    if (h == 0) {
        float acc = 0.f;
#pragma unroll
        for (int d = 0; d < D_; ++d)
            acc = fmaf(Ts[0][d][c] + Ts[1][d][c], Ws[d * C_ + c], acc);
        y1[((size_t)m * O_ + o) * C_ + c] = acc;
    }
}

// out[m,p,c] = (sum_o y1[m,o,c] * rk[p,o,c]) / 12 + bias[c]
__global__ __launch_bounds__(256) void fiber_kernel(
    const float* __restrict__ y1, const float* __restrict__ rk,
    const float* __restrict__ bias, float* __restrict__ out)
{
    int idx = blockIdx.x * 256 + threadIdx.x;
    if (idx >= M_ * O_ * C_) return;
    int c = idx & (C_ - 1);
    int p = (idx >> 7) % O_;
    int m = idx / (O_ * C_);
    float acc = 0.f;
#pragma unroll
    for (int o = 0; o < O_; ++o)
        acc = fmaf(y1[(m * O_ + o) * C_ + c], rk[(p * O_ + o) * C_ + c], acc);
    out[idx] = acc * (1.0f / 12.0f) + bias[c];
}

extern "C" void kernel_launch(void* const* d_in, const int* in_sizes, int n_in,
                              void* d_out, int out_size, void* d_ws, size_t ws_size,
                              hipStream_t stream)
{
    const float* x    = (const float*)d_in[0];  // (1,256,12,128)
    const float* kb   = (const float*)d_in[1];  // (1,256,256,12,32)
    const float* fkb  = (const float*)d_in[2];  // (12,12,32)
    const float* mask = (const float*)d_in[3];  // (1,256)
    const float* Wsp  = (const float*)d_in[4];  // (32,128)
    const float* Wrt  = (const float*)d_in[5];  // (32,128)
    const float* bias = (const float*)d_in[6];  // (128,)
    float* out = (float*)d_out;                 // (1,256,12,128)

    float* rk = (float*)d_ws;                   // O*O*C   = 18432 floats
    float* y1 = (float*)d_ws + (O_ * O_ * C_);  // M*O*C   = 393216 floats

    rot_proj_kernel<<<(O_ * O_ * C_ + 255) / 256, 256, 0, stream>>>(fkb, Wrt, rk);
    spatial_kernel<<<M_ * O_, 256, 0, stream>>>(x, kb, mask, Wsp, y1);
    fiber_kernel<<<(M_ * O_ * C_ + 255) / 256, 256, 0, stream>>>(y1, rk, bias, out);
}

// Round 2
// 70.366 us; speedup vs baseline: 1.8251x; 1.8251x over previous
//
#include <hip/hip_runtime.h>

// Shapes (fixed by the reference): B=1, M=N=256, O=P=12, C=128, D=32
#define N_ 256
#define M_ 256
#define O_ 12
#define C_ 128
#define D_ 32
#define S_ 8      // K-splits of the spatial GEMM (K=8192 -> 8 chunks of 1024)
#define BM 32     // M-tile of spatial GEMM
#define NSTEP 16  // K-steps per block: BK=64 (=2 n-rows of 32 d) x 16 = 1024

typedef __attribute__((ext_vector_type(8))) short short8;   // 8 x bf16 (4 VGPR)
typedef __attribute__((ext_vector_type(4))) float floatx4;  // MFMA acc

static __device__ __forceinline__ short f2bf(float f) {
    unsigned u = __float_as_uint(f);
    unsigned r = u + 0x7FFFu + ((u >> 16) & 1u);  // RNE
    return (short)(r >> 16);
}

// ---------------- rk[p,o,c] = sum_d fkb[p,o,d] * Wr[d,c] ----------------
__global__ __launch_bounds__(256) void rot_proj_kernel(
    const float* __restrict__ fkb, const float* __restrict__ Wr,
    float* __restrict__ rk)
{
    int idx = blockIdx.x * 256 + threadIdx.x;
    if (idx >= O_ * O_ * C_) return;
    int c  = idx & (C_ - 1);
    int po = idx >> 7;
    const float* f = fkb + po * D_;
    float acc = 0.f;
#pragma unroll
    for (int d = 0; d < D_; ++d) acc = fmaf(f[d], Wr[d * C_ + c], acc);
    rk[idx] = acc;
}

// ---------------- g[o][n][c][d] = bf16( x[n,o,c]*mask[n]*Ws[d,c] ) ------
__global__ __launch_bounds__(256) void g_kernel(
    const float* __restrict__ x, const float* __restrict__ mask,
    const float* __restrict__ Ws, short* __restrict__ g)
{
    const int n = blockIdx.x;        // 256
    const int o = blockIdx.y;        // 12
    const int t = threadIdx.x;
    const int c  = t >> 1;           // 0..127
    const int dh = (t & 1) * 16;     // 0 or 16
    const float xm = x[(n * O_ + o) * C_ + c] * mask[n];
    short8 w0, w1;
#pragma unroll
    for (int i = 0; i < 8; ++i) w0[i] = f2bf(xm * Ws[(dh + i) * C_ + c]);
#pragma unroll
    for (int i = 0; i < 8; ++i) w1[i] = f2bf(xm * Ws[(dh + 8 + i) * C_ + c]);
    short* gp = g + (((size_t)(o * N_ + n)) * C_ + c) * D_ + dh;
    *reinterpret_cast<short8*>(gp)     = w0;
    *reinterpret_cast<short8*>(gp + 8) = w1;
}

// ---------------- spatial GEMM: part[s][m][o][c] += kb x g --------------
// Per o: y1[m,c] = sum_{k=(n,d)} kb[m,n,o,d] * g[o,n,c,d].  M=256,N=128,K=8192.
// Block: BM=32 x BN=128, K-chunk 1024. 4 waves, each 32x32 output.
__global__ __launch_bounds__(256) void spatial_mfma_kernel(
    const float* __restrict__ kb, const short* __restrict__ g,
    float* __restrict__ part)
{
    const int mt  = blockIdx.x;   // 0..7
    const int o   = blockIdx.y;   // 0..11
    const int sck = blockIdx.z;   // 0..7
    const int t    = threadIdx.x;
    const int lane = t & 63;
    const int wave = t >> 6;

    const int m0    = mt * BM;
    const int nbase = sck * 32;

    __shared__ __align__(16) short Alds[BM * 64];  // 4 KB, XOR-swizzled

    // --- staging-side constants (thread t stages 8 consecutive kk of one row)
    const int srow = t >> 3;                 // 0..31 (local m row)
    const int sch  = t & 7;                  // chunk: kk0 = sch*8
    const int swz_wr = srow * 64 + ((sch ^ (srow & 7)) * 8);   // short index
    const int s_nloc = sch >> 2;             // which n of the BK=64 pair
    const int s_d0   = (sch & 3) * 8;        // d offset within the n
    const float* kb_t = kb + (size_t)(m0 + srow) * (N_ * O_ * D_) + o * D_ + s_d0;

    // --- MFMA-side constants
    const int l15 = lane & 15;
    const int lk  = lane >> 4;               // 0..3 -> k-group (8 consecutive k)
    const int bd0 = lk * 8;
    // B: direct-from-global fragments; per (n, col): g[o][n][col][bd0..bd0+7]
    const short* gb = g + (size_t)o * (N_ * C_ * D_);
    const short* g0 = gb + (wave * 32 + l15) * D_ + bd0;        // nrep 0 col
    const short* g1 = gb + (wave * 32 + 16 + l15) * D_ + bd0;   // nrep 1 col
    const int ar0 = l15, ar1 = 16 + l15;     // A rows for mrep 0/1
    const int aswz = l15 & 7;

    floatx4 acc[2][2];
#pragma unroll
    for (int i = 0; i < 2; ++i)
#pragma unroll
        for (int j = 0; j < 2; ++j)
#pragma unroll
            for (int q = 0; q < 4; ++q) acc[i][j][q] = 0.f;

    // prologue: stage step 0
    floatx4 pa0, pa1;
    {
        const float* p = kb_t + (size_t)(nbase + s_nloc) * (O_ * D_);
        pa0 = *reinterpret_cast<const floatx4*>(p);
        pa1 = *reinterpret_cast<const floatx4*>(p + 4);
        short8 w;
#pragma unroll
        for (int q = 0; q < 4; ++q) { w[q] = f2bf(pa0[q]); w[4 + q] = f2bf(pa1[q]); }
        *reinterpret_cast<short8*>(&Alds[swz_wr]) = w;
    }

    for (int s = 0; s < NSTEP; ++s) {
        __syncthreads();  // staged tile visible
        if (s + 1 < NSTEP) {  // prefetch next A into regs (hides under MFMA)
            const float* p = kb_t + (size_t)(nbase + 2 * (s + 1) + s_nloc) * (O_ * D_);
            pa0 = *reinterpret_cast<const floatx4*>(p);
            pa1 = *reinterpret_cast<const floatx4*>(p + 4);
        }
#pragma unroll
        for (int ksub = 0; ksub < 2; ++ksub) {
            const size_t n = nbase + 2 * s + ksub;
            short8 b0 = *reinterpret_cast<const short8*>(g0 + n * (C_ * D_));
            short8 b1 = *reinterpret_cast<const short8*>(g1 + n * (C_ * D_));
            short8 a0 = *reinterpret_cast<const short8*>(
                &Alds[ar0 * 64 + (((ksub * 4 + lk) ^ aswz) * 8)]);
            short8 a1 = *reinterpret_cast<const short8*>(
                &Alds[ar1 * 64 + (((ksub * 4 + lk) ^ aswz) * 8)]);
            acc[0][0] = __builtin_amdgcn_mfma_f32_16x16x32_bf16(a0, b0, acc[0][0], 0, 0, 0);
            acc[0][1] = __builtin_amdgcn_mfma_f32_16x16x32_bf16(a0, b1, acc[0][1], 0, 0, 0);
            acc[1][0] = __builtin_amdgcn_mfma_f32_16x16x32_bf16(a1, b0, acc[1][0], 0, 0, 0);
            acc[1][1] = __builtin_amdgcn_mfma_f32_16x16x32_bf16(a1, b1, acc[1][1], 0, 0, 0);
        }
        __syncthreads();  // all LDS reads of step s done
        if (s + 1 < NSTEP) {
            short8 w;
#pragma unroll
            for (int q = 0; q < 4; ++q) { w[q] = f2bf(pa0[q]); w[4 + q] = f2bf(pa1[q]); }
            *reinterpret_cast<short8*>(&Alds[swz_wr]) = w;
        }
    }

    // epilogue: C/D layout col=lane&15, row=(lane>>4)*4+reg  [m89-verified]
#pragma unroll
    for (int mr = 0; mr < 2; ++mr)
#pragma unroll
        for (int nr = 0; nr < 2; ++nr) {
            const int col = wave * 32 + nr * 16 + l15;
#pragma unroll
            for (int j = 0; j < 4; ++j) {
                const int row = m0 + mr * 16 + lk * 4 + j;
                part[(((size_t)sck * M_ + row) * O_ + o) * C_ + col] = acc[mr][nr][j];
            }
        }
}

// ---- out[m,p,c] = (sum_o (sum_s part[s,m,o,c]) * rk[p,o,c])/12 + bias[c]
__global__ __launch_bounds__(256) void fiber2_kernel(
    const float* __restrict__ part, const float* __restrict__ rkv,
    const float* __restrict__ bias, float* __restrict__ out)
{
    const int m = blockIdx.x;
    const int t = threadIdx.x;
    const int c = t & 127;
    const int half = t >> 7;
    float y1v[O_];
#pragma unroll
    for (int o = 0; o < O_; ++o) {
        float a = 0.f;
#pragma unroll
        for (int s = 0; s < S_; ++s)
            a += part[(((size_t)s * M_ + m) * O_ + o) * C_ + c];
        y1v[o] = a;
    }
#pragma unroll
    for (int pp = 0; pp < O_ / 2; ++pp) {
        const int p = half * (O_ / 2) + pp;
        float a = 0.f;
#pragma unroll
        for (int o = 0; o < O_; ++o)
            a = fmaf(y1v[o], rkv[(p * O_ + o) * C_ + c], a);
        out[((size_t)m * O_ + p) * C_ + c] = a * (1.f / 12.f) + bias[c];
    }
}

// ---------------- fallback (round-1) path, used only if ws is small ------
__global__ __launch_bounds__(256) void spatial_old_kernel(
    const float* __restrict__ x, const float* __restrict__ kb,
    const float* __restrict__ mask, const float* __restrict__ Ws,
    float* __restrict__ y1)
{
    const int bid = blockIdx.x;
    const int m = bid / O_, o = bid % O_;
    const int tid = threadIdx.x;
    const int h = tid >> 7, c = tid & (C_ - 1);
    __shared__ float kbs[2][8][D_];
    __shared__ float msk[N_];
    __shared__ float Ts[2][D_][C_];
    msk[tid] = mask[tid];
    float T[D_];
#pragma unroll
    for (int d = 0; d < D_; ++d) T[d] = 0.f;
    const float* kb_mo = kb + (size_t)m * (N_ * O_ * D_) + o * D_;
    const int j_ld = c >> 4, d_ld = (c & 15) * 2;
    for (int chunk = 0; chunk < 16; ++chunk) {
        const int n0 = h * 128 + chunk * 8;
        __syncthreads();
        float2 v = *reinterpret_cast<const float2*>(
            kb_mo + (size_t)(n0 + j_ld) * (O_ * D_) + d_ld);
        kbs[h][j_ld][d_ld] = v.x;
        kbs[h][j_ld][d_ld + 1] = v.y;
        __syncthreads();
#pragma unroll
        for (int j = 0; j < 8; ++j) {
            const int n = n0 + j;
            const float xv = x[(n * O_ + o) * C_ + c] * msk[n];
#pragma unroll
            for (int d = 0; d < D_; ++d) T[d] = fmaf(kbs[h][j][d], xv, T[d]);
        }
    }
#pragma unroll
    for (int d = 0; d < D_; ++d) Ts[h][d][c] = T[d];
    __syncthreads();
    if (h == 0) {
        float a = 0.f;
#pragma unroll
        for (int d = 0; d < D_; ++d)
            a = fmaf(Ts[0][d][c] + Ts[1][d][c], Ws[d * C_ + c], a);
        y1[((size_t)m * O_ + o) * C_ + c] = a;
    }
}

__global__ __launch_bounds__(256) void fiber_old_kernel(
    const float* __restrict__ y1, const float* __restrict__ rkv,
    const float* __restrict__ bias, float* __restrict__ out)
{
    int idx = blockIdx.x * 256 + threadIdx.x;
    if (idx >= M_ * O_ * C_) return;
    int c = idx & (C_ - 1);
    int p = (idx >> 7) % O_;
    int m = idx / (O_ * C_);
    float a = 0.f;
#pragma unroll
    for (int o = 0; o < O_; ++o)
        a = fmaf(y1[(m * O_ + o) * C_ + c], rkv[(p * O_ + o) * C_ + c], a);
    out[idx] = a * (1.0f / 12.0f) + bias[c];
}

extern "C" void kernel_launch(void* const* d_in, const int* in_sizes, int n_in,
                              void* d_out, int out_size, void* d_ws, size_t ws_size,
                              hipStream_t stream)
{
    const float* x    = (const float*)d_in[0];  // (1,256,12,128)
    const float* kb   = (const float*)d_in[1];  // (1,256,256,12,32)
    const float* fkb  = (const float*)d_in[2];  // (12,12,32)
    const float* mask = (const float*)d_in[3];  // (1,256)
    const float* Wsp  = (const float*)d_in[4];  // (32,128)
    const float* Wrt  = (const float*)d_in[5];  // (32,128)
    const float* bias = (const float*)d_in[6];  // (128,)
    float* out = (float*)d_out;                 // (1,256,12,128)

    const size_t RK_F   = (size_t)O_ * O_ * C_;            // 18432 floats
    const size_t PART_F = (size_t)S_ * M_ * O_ * C_;       // 3145728 floats
    const size_t G_E    = (size_t)O_ * N_ * C_ * D_;       // 12582912 bf16
    const size_t need   = (RK_F + PART_F) * 4 + G_E * 2;   // ~37.8 MB

    float* rk = (float*)d_ws;

    rot_proj_kernel<<<(O_ * O_ * C_ + 255) / 256, 256, 0, stream>>>(fkb, Wrt, rk);

    if (ws_size >= need) {
        float* part = rk + RK_F;
        short* g    = (short*)(part + PART_F);
        g_kernel<<<dim3(N_, O_), 256, 0, stream>>>(x, mask, Wsp, g);
        spatial_mfma_kernel<<<dim3(M_ / BM, O_, S_), 256, 0, stream>>>(kb, g, part);
        fiber2_kernel<<<M_, 256, 0, stream>>>(part, rk, bias, out);
    } else {
        float* y1 = rk + RK_F;
        spatial_old_kernel<<<M_ * O_, 256, 0, stream>>>(x, kb, mask, Wsp, y1);
        fiber_old_kernel<<<(M_ * O_ * C_ + 255) / 256, 256, 0, stream>>>(y1, rk, bias, out);
    }
}